// Round 6
// baseline (33.253 us; speedup 1.0000x reference)
//
#include <hip/hip_runtime.h>
#include <stdint.h>

// Problem constants (from reference):
#define T_DIM 1024
#define B_DIM 8
#define C_DIM 1024
#define H_DIM 16
#define K_SZ  7
#define P_PAD 3
#define O_DIM (H_DIM * K_SZ)   // 112
#define TB    (T_DIM * B_DIM)  // 8192 rows

typedef __attribute__((ext_vector_type(8))) short bf16x8;  // 4 VGPRs, 8 bf16
typedef __attribute__((ext_vector_type(4))) float f32x4;
typedef __attribute__((ext_vector_type(4))) uint32_t u32x4;

union FragU { uint32_t u[4]; bf16x8 v; };

// RNE fp32->bf16 pack of two floats into one dword (lo=a, hi=b)
__device__ inline uint32_t pk_bf16(float a, float b) {
  uint32_t ua = __float_as_uint(a), ub = __float_as_uint(b);
  ua += 0x7FFFu + ((ua >> 16) & 1u);
  ub += 0x7FFFu + ((ub >> 16) & 1u);
  return (ua >> 16) | (ub & 0xFFFF0000u);
}

__device__ inline bf16x8 load_bf16x8_cvt(const float* __restrict__ p) {
  float4 lo = *reinterpret_cast<const float4*>(p);
  float4 hi = *reinterpret_cast<const float4*>(p + 4);
  FragU f;
  f.u[0] = pk_bf16(lo.x, lo.y);
  f.u[1] = pk_bf16(lo.z, lo.w);
  f.u[2] = pk_bf16(hi.x, hi.y);
  f.u[3] = pk_bf16(hi.z, hi.w);
  return f.v;
}

// Kernel 0: build fragment-native bf16 W.
// Wf[((ks*7)+nf)*64 + lane] (16B) = W[nf*16+(lane&15)][ks*32+(lane>>4)*8 .. +7]
__global__ __launch_bounds__(256) void prep_wfrag_kernel(
    const float* __restrict__ Wl, uint16_t* __restrict__ Wf) {
  const int t  = blockIdx.x * 256 + threadIdx.x;  // 0..14335
  const int f  = t >> 6;
  const int l  = t & 63;
  const int ks = f / 7;
  const int nf = f - ks * 7;
  const int row = nf * 16 + (l & 15);
  const int kb  = ks * 32 + (l >> 4) * 8;
  bf16x8 v = load_bf16x8_cvt(Wl + (size_t)row * C_DIM + kb);
  *reinterpret_cast<bf16x8*>(Wf + (size_t)t * 8) = v;   // coalesced 16B/lane
}

// Fused kernel, t-major tiles: block owns rows (t0..t0+15, b) for one b.
//  phase 1: stage 22 x rows (16 main + 6 halo) -> bf16 LDS, XOR-swizzled
//  phase 2: logits MFMA; waves split the 7 col-fragments (full K each,
//           partials written ONCE -- no cross-wave reduce)
//  phase 3: bias + softmax -> wsm[16][17][8] (padded, bank-spread)
//  phase 4: conv entirely from LDS taps (bf16) + coalesced out stores
template <bool PREPPED>
__global__ __launch_bounds__(256) void fused_dynconv_kernel(
    const float* __restrict__ x, const float* __restrict__ Wl,
    const uint16_t* __restrict__ Wf, const float* __restrict__ bl,
    const float* __restrict__ cb, float* __restrict__ out) {
  __shared__ char  xbf[22 * 2048];     // 22 rows x 1024ch bf16, swizzled (44KB)
  __shared__ float part[16][116];      // logits, written once (7.4KB)
  __shared__ float wsm[16][17][8];     // softmax w, [row][head][tap] (8.7KB)

  const int tid  = threadIdx.x;
  const int wv   = tid >> 6;
  const int lane = tid & 63;
  const int l15  = lane & 15;
  const int oct  = lane >> 4;

  // XCD-chunk swizzle: xcd = bid&7 owns 8 contiguous t-tiles for every b.
  const int bid    = blockIdx.x;       // 0..511
  const int w8     = bid >> 3;
  const int t_tile = (bid & 7) * 8 + (w8 & 7);
  const int b      = w8 >> 3;
  const int t0     = t_tile * 16;

  // --- phase 1: stage rows t0-3 .. t0+18 (clamped) as bf16, swizzled ---
  {
#pragma unroll
    for (int it = 0; it < 11; ++it) {
      const int task = tid + it * 256;        // 22 rows x 128 chunks
      const int q    = task >> 7;
      const int c16  = task & 127;            // 8-channel chunk
      const int trow = min(max(t0 + q - P_PAD, 0), T_DIM - 1);
      const float* __restrict__ src =
          x + ((size_t)(trow * B_DIM + b)) * C_DIM + c16 * 8;
      float4 v0 = *reinterpret_cast<const float4*>(src);
      float4 v1 = *reinterpret_cast<const float4*>(src + 4);
      FragU f;
      f.u[0] = pk_bf16(v0.x, v0.y);
      f.u[1] = pk_bf16(v0.z, v0.w);
      f.u[2] = pk_bf16(v1.x, v1.y);
      f.u[3] = pk_bf16(v1.z, v1.w);
      const int dst = q * 2048 + ((c16 * 16) ^ ((q & 7) << 4));
      *reinterpret_cast<bf16x8*>(xbf + dst) = f.v;
    }
  }
  __syncthreads();

  // --- phase 2: MFMA, col-fragment split across waves, full K ---
  {
    const int nf0 = wv * 2;                 // wave3 -> nf 6 only
    const int nfc = (wv == 3) ? 1 : 2;
    f32x4 acc0 = (f32x4)(0.f), acc1 = (f32x4)(0.f);
    const int arow  = 3 + l15;              // main rows are q=3..18
    const int abase = arow * 2048;
    const int axor  = (arow & 7) << 4;
#pragma unroll
    for (int ks = 0; ks < 32; ++ks) {
      bf16x8 a = *reinterpret_cast<const bf16x8*>(
          xbf + abase + ((ks * 64 + oct * 16) ^ axor));
      bf16x8 b0, b1;
      if (PREPPED) {
        b0 = *reinterpret_cast<const bf16x8*>(
            Wf + ((size_t)((ks * 7 + nf0) * 64) + lane) * 8);
        if (nfc == 2)
          b1 = *reinterpret_cast<const bf16x8*>(
              Wf + ((size_t)((ks * 7 + nf0 + 1) * 64) + lane) * 8);
      } else {
        b0 = load_bf16x8_cvt(Wl + (size_t)(nf0 * 16 + l15) * C_DIM + ks * 32 + oct * 8);
        if (nfc == 2)
          b1 = load_bf16x8_cvt(Wl + (size_t)((nf0 + 1) * 16 + l15) * C_DIM + ks * 32 + oct * 8);
      }
      acc0 = __builtin_amdgcn_mfma_f32_16x16x32_bf16(a, b0, acc0, 0, 0, 0);
      if (nfc == 2)
        acc1 = __builtin_amdgcn_mfma_f32_16x16x32_bf16(a, b1, acc1, 0, 0, 0);
    }
    // D layout: col = lane&15 (W row), row = (lane>>4)*4 + reg (x row)
#pragma unroll
    for (int r = 0; r < 4; ++r)
      part[oct * 4 + r][nf0 * 16 + l15] = acc0[r];
    if (nfc == 2) {
#pragma unroll
      for (int r = 0; r < 4; ++r)
        part[oct * 4 + r][(nf0 + 1) * 16 + l15] = acc1[r];
    }
  }
  __syncthreads();

  // --- phase 3: bias + softmax over 7 taps -> wsm ---
  {
    const int row = tid >> 4;
    const int h   = tid & 15;
    float lg[7];
    float m = -1e30f;
#pragma unroll
    for (int j = 0; j < 7; ++j) {
      float s_ = part[row][h * 7 + j] + bl[h * 7 + j];
      lg[j] = s_;
      m = fmaxf(m, s_);
    }
    float s = 0.f;
#pragma unroll
    for (int j = 0; j < 7; ++j) { lg[j] = __expf(lg[j] - m); s += lg[j]; }
    const float inv = 1.0f / s;
#pragma unroll
    for (int j = 0; j < 7; ++j) wsm[row][h][j] = lg[j] * inv;
  }
  __syncthreads();

  // --- phase 4: conv from LDS taps; thread (row,t15) does 8 ch per ii ---
  {
    const int row   = tid >> 4;
    const int t15   = tid & 15;
    const int tglob = t0 + row;
    float okf[7];
#pragma unroll
    for (int j = 0; j < 7; ++j) {
      int tp = tglob + j - P_PAD;
      okf[j] = (tp >= 0 && tp < T_DIM) ? 1.f : 0.f;
    }
    float* __restrict__ obase = out + ((size_t)(tglob * B_DIM + b)) * C_DIM;

#pragma unroll
    for (int ii = 0; ii < 8; ++ii) {
      const int ch0  = ii * 128 + t15 * 8;
      const int head = ii * 2 + (t15 >> 3);
      float4 w0 = *reinterpret_cast<const float4*>(&wsm[row][head][0]);
      float4 w1 = *reinterpret_cast<const float4*>(&wsm[row][head][4]);
      const float wj[7] = {w0.x, w0.y, w0.z, w0.w, w1.x, w1.y, w1.z};
      float4 c0 = *reinterpret_cast<const float4*>(cb + ch0);
      float4 c1 = *reinterpret_cast<const float4*>(cb + ch0 + 4);
      float a0 = c0.x, a1 = c0.y, a2 = c0.z, a3 = c0.w;
      float a4 = c1.x, a5 = c1.y, a6 = c1.z, a7 = c1.w;
#pragma unroll
      for (int j = 0; j < 7; ++j) {
        const float w = wj[j] * okf[j];
        const int q = row + j;                         // hx row = tap
        const u32x4 d = *reinterpret_cast<const u32x4*>(
            xbf + q * 2048 + ((ii * 256 + t15 * 16) ^ ((q & 7) << 4)));
        a0 += w * __uint_as_float(d.x << 16);
        a1 += w * __uint_as_float(d.x & 0xffff0000u);
        a2 += w * __uint_as_float(d.y << 16);
        a3 += w * __uint_as_float(d.y & 0xffff0000u);
        a4 += w * __uint_as_float(d.z << 16);
        a5 += w * __uint_as_float(d.z & 0xffff0000u);
        a6 += w * __uint_as_float(d.w << 16);
        a7 += w * __uint_as_float(d.w & 0xffff0000u);
      }
      *reinterpret_cast<float4*>(obase + ch0)     = make_float4(a0, a1, a2, a3);
      *reinterpret_cast<float4*>(obase + ch0 + 4) = make_float4(a4, a5, a6, a7);
    }
  }
}

extern "C" void kernel_launch(void* const* d_in, const int* in_sizes, int n_in,
                              void* d_out, int out_size, void* d_ws, size_t ws_size,
                              hipStream_t stream) {
  const float* x  = (const float*)d_in[0];   // (T,B,C)
  const float* Wl = (const float*)d_in[1];   // (H*K, C)
  const float* bl = (const float*)d_in[2];   // (H*K,)
  const float* cb = (const float*)d_in[3];   // (C,)
  float* out = (float*)d_out;                // (T,B,C)

  const bool prepped = ws_size >= 262144;    // 224KB frag-W, padded

  if (prepped) {
    uint16_t* wf = (uint16_t*)d_ws;
    prep_wfrag_kernel<<<(32 * 7 * 64) / 256, 256, 0, stream>>>(Wl, wf);
    fused_dynconv_kernel<true><<<TB / 16, 256, 0, stream>>>(x, Wl, wf, bl, cb, out);
  } else {
    fused_dynconv_kernel<false><<<TB / 16, 256, 0, stream>>>(x, Wl, nullptr, bl, cb, out);
  }
}

// Round 7
// 30.213 us; speedup vs baseline: 1.1006x; 1.1006x over previous
//
#include <hip/hip_runtime.h>
#include <stdint.h>

// Problem constants (from reference):
#define T_DIM 1024
#define B_DIM 8
#define C_DIM 1024
#define H_DIM 16
#define K_SZ  7
#define P_PAD 3
#define O_DIM (H_DIM * K_SZ)   // 112
#define TB    (T_DIM * B_DIM)  // 8192 rows

typedef __attribute__((ext_vector_type(8))) short bf16x8;  // 4 VGPRs, 8 bf16
typedef __attribute__((ext_vector_type(4))) float f32x4;
typedef __attribute__((ext_vector_type(4))) uint32_t u32x4;

union FragU { uint32_t u[4]; bf16x8 v; };

// RNE fp32->bf16 pack of two floats into one dword (lo=a, hi=b)
__device__ inline uint32_t pk_bf16(float a, float b) {
  uint32_t ua = __float_as_uint(a), ub = __float_as_uint(b);
  ua += 0x7FFFu + ((ua >> 16) & 1u);
  ub += 0x7FFFu + ((ub >> 16) & 1u);
  return (ua >> 16) | (ub & 0xFFFF0000u);
}

__device__ inline bf16x8 load_bf16x8_cvt(const float* __restrict__ p) {
  float4 lo = *reinterpret_cast<const float4*>(p);
  float4 hi = *reinterpret_cast<const float4*>(p + 4);
  FragU f;
  f.u[0] = pk_bf16(lo.x, lo.y);
  f.u[1] = pk_bf16(lo.z, lo.w);
  f.u[2] = pk_bf16(hi.x, hi.y);
  f.u[3] = pk_bf16(hi.z, hi.w);
  return f.v;
}

// Kernel 0: build fragment-native bf16 W.
// Wf[((ks*7)+nf)*64 + lane] (16B) = W[nf*16+(lane&15)][ks*32+(lane>>4)*8 .. +7]
__global__ __launch_bounds__(256) void prep_wfrag_kernel(
    const float* __restrict__ Wl, uint16_t* __restrict__ Wf) {
  const int t  = blockIdx.x * 256 + threadIdx.x;  // 0..14335
  const int f  = t >> 6;
  const int l  = t & 63;
  const int ks = f / 7;
  const int nf = f - ks * 7;
  const int row = nf * 16 + (l & 15);
  const int kb  = ks * 32 + (l >> 4) * 8;
  bf16x8 v = load_bf16x8_cvt(Wl + (size_t)row * C_DIM + kb);
  *reinterpret_cast<bf16x8*>(Wf + (size_t)t * 8) = v;   // coalesced 16B/lane
}

// Fused kernel, t-major tiles, 512 threads (8 waves) per block:
//  block owns rows (t0..t0+15) x one b. 512 blocks = 2/CU = 16 waves/CU.
//  phase 1: stage 22 x-rows (16 main + 6 halo) -> bf16 LDS, XOR-swizzled
//  phase 2: logits MFMA; wave = (K-half, nf-quad): 2-way K x 4-way nf split,
//           16 ks-steps each, partials to part[2]
//  phase 3: 2-way reduce + bias + softmax -> wsm (tid<256)
//  phase 4: conv fully from LDS bf16 taps; coalesced fp32 out stores
template <bool PREPPED>
__global__ __launch_bounds__(512) void fused_dynconv_kernel(
    const float* __restrict__ x, const float* __restrict__ Wl,
    const uint16_t* __restrict__ Wf, const float* __restrict__ bl,
    const float* __restrict__ cb, float* __restrict__ out) {
  __shared__ char  xbf[22 * 2048];     // 22 rows x 1024ch bf16, swizzled (44KB)
  __shared__ float part[2][16][116];   // per-K-half logits (14.5KB)
  __shared__ float wsm[16][17][8];     // softmax w, [row][head][tap] (8.7KB)

  const int tid  = threadIdx.x;
  const int wv   = tid >> 6;           // 0..7
  const int lane = tid & 63;
  const int l15  = lane & 15;
  const int oct  = lane >> 4;

  // XCD-chunk swizzle: xcd = bid&7 owns contiguous t-range for every b.
  const int bid    = blockIdx.x;       // 0..511
  const int w8     = bid >> 3;
  const int t_tile = (bid & 7) * 8 + (w8 & 7);
  const int b      = w8 >> 3;
  const int t0     = t_tile * 16;

  // --- phase 1: stage rows t0-3 .. t0+18 (clamped) as bf16, swizzled ---
  {
#pragma unroll
    for (int it = 0; it < 6; ++it) {
      const int task = tid + it * 512;        // 22 rows x 128 chunks = 2816
      if (task < 22 * 128) {
        const int q    = task >> 7;
        const int c16  = task & 127;          // 8-channel chunk
        const int trow = min(max(t0 + q - P_PAD, 0), T_DIM - 1);
        const float* __restrict__ src =
            x + ((size_t)(trow * B_DIM + b)) * C_DIM + c16 * 8;
        float4 v0 = *reinterpret_cast<const float4*>(src);
        float4 v1 = *reinterpret_cast<const float4*>(src + 4);
        FragU f;
        f.u[0] = pk_bf16(v0.x, v0.y);
        f.u[1] = pk_bf16(v0.z, v0.w);
        f.u[2] = pk_bf16(v1.x, v1.y);
        f.u[3] = pk_bf16(v1.z, v1.w);
        const int dst = q * 2048 + ((c16 * 16) ^ ((q & 7) << 4));
        *reinterpret_cast<bf16x8*>(xbf + dst) = f.v;
      }
    }
  }
  __syncthreads();

  // --- phase 2: MFMA; wave = (K-half kh, nf-quad nfq) ---
  {
    const int kh  = wv >> 2;               // K rows kh*512 .. +511
    const int nfq = wv & 3;
    const int nf0 = nfq * 2;               // nfq 3 -> nf 6 only
    const int nfc = (nfq == 3) ? 1 : 2;
    f32x4 acc0 = (f32x4)(0.f), acc1 = (f32x4)(0.f);
    const int arow  = 3 + l15;             // main rows are q=3..18
    const int abase = arow * 2048;
    const int axor  = (arow & 7) << 4;
#pragma unroll
    for (int s = 0; s < 16; ++s) {
      const int ksg = kh * 16 + s;         // global 32-wide K step
      bf16x8 a = *reinterpret_cast<const bf16x8*>(
          xbf + abase + ((ksg * 64 + oct * 16) ^ axor));
      bf16x8 b0, b1;
      if (PREPPED) {
        b0 = *reinterpret_cast<const bf16x8*>(
            Wf + ((size_t)((ksg * 7 + nf0) * 64) + lane) * 8);
        if (nfc == 2)
          b1 = *reinterpret_cast<const bf16x8*>(
              Wf + ((size_t)((ksg * 7 + nf0 + 1) * 64) + lane) * 8);
      } else {
        b0 = load_bf16x8_cvt(Wl + (size_t)(nf0 * 16 + l15) * C_DIM + ksg * 32 + oct * 8);
        if (nfc == 2)
          b1 = load_bf16x8_cvt(Wl + (size_t)((nf0 + 1) * 16 + l15) * C_DIM + ksg * 32 + oct * 8);
      }
      acc0 = __builtin_amdgcn_mfma_f32_16x16x32_bf16(a, b0, acc0, 0, 0, 0);
      if (nfc == 2)
        acc1 = __builtin_amdgcn_mfma_f32_16x16x32_bf16(a, b1, acc1, 0, 0, 0);
    }
    // D layout: col = lane&15 (W row), row = (lane>>4)*4 + reg (x row)
#pragma unroll
    for (int r = 0; r < 4; ++r)
      part[kh][oct * 4 + r][nf0 * 16 + l15] = acc0[r];
    if (nfc == 2) {
#pragma unroll
      for (int r = 0; r < 4; ++r)
        part[kh][oct * 4 + r][(nf0 + 1) * 16 + l15] = acc1[r];
    }
  }
  __syncthreads();

  // --- phase 3: 2-way reduce + bias + softmax -> wsm (first 4 waves) ---
  if (tid < 256) {
    const int row = tid >> 4;
    const int h   = tid & 15;
    float lg[7];
    float m = -1e30f;
#pragma unroll
    for (int j = 0; j < 7; ++j) {
      const int c = h * 7 + j;
      float s_ = part[0][row][c] + part[1][row][c] + bl[c];
      lg[j] = s_;
      m = fmaxf(m, s_);
    }
    float s = 0.f;
#pragma unroll
    for (int j = 0; j < 7; ++j) { lg[j] = __expf(lg[j] - m); s += lg[j]; }
    const float inv = 1.0f / s;
#pragma unroll
    for (int j = 0; j < 7; ++j) wsm[row][h][j] = lg[j] * inv;
  }
  __syncthreads();

  // --- phase 4: conv from LDS taps; thread (row, t32) does 8 ch per ii ---
  {
    const int row   = tid >> 5;            // 0..15
    const int t32   = tid & 31;
    const int tglob = t0 + row;
    float okf[7];
#pragma unroll
    for (int j = 0; j < 7; ++j) {
      int tp = tglob + j - P_PAD;
      okf[j] = (tp >= 0 && tp < T_DIM) ? 1.f : 0.f;
    }
    float* __restrict__ obase = out + ((size_t)(tglob * B_DIM + b)) * C_DIM;

#pragma unroll
    for (int ii = 0; ii < 4; ++ii) {
      const int ch0  = ii * 256 + t32 * 8;
      const int head = ch0 >> 6;           // ii*4 + (t32>>3)
      float4 w0 = *reinterpret_cast<const float4*>(&wsm[row][head][0]);
      float4 w1 = *reinterpret_cast<const float4*>(&wsm[row][head][4]);
      const float wj[7] = {w0.x, w0.y, w0.z, w0.w, w1.x, w1.y, w1.z};
      float4 c0 = *reinterpret_cast<const float4*>(cb + ch0);
      float4 c1 = *reinterpret_cast<const float4*>(cb + ch0 + 4);
      float a0 = c0.x, a1 = c0.y, a2 = c0.z, a3 = c0.w;
      float a4 = c1.x, a5 = c1.y, a6 = c1.z, a7 = c1.w;
#pragma unroll
      for (int j = 0; j < 7; ++j) {
        const float w = wj[j] * okf[j];
        const int q = row + j;             // staged row = tap
        const u32x4 d = *reinterpret_cast<const u32x4*>(
            xbf + q * 2048 + ((ch0 * 2) ^ ((q & 7) << 4)));
        a0 += w * __uint_as_float(d.x << 16);
        a1 += w * __uint_as_float(d.x & 0xffff0000u);
        a2 += w * __uint_as_float(d.y << 16);
        a3 += w * __uint_as_float(d.y & 0xffff0000u);
        a4 += w * __uint_as_float(d.z << 16);
        a5 += w * __uint_as_float(d.z & 0xffff0000u);
        a6 += w * __uint_as_float(d.w << 16);
        a7 += w * __uint_as_float(d.w & 0xffff0000u);
      }
      *reinterpret_cast<float4*>(obase + ch0)     = make_float4(a0, a1, a2, a3);
      *reinterpret_cast<float4*>(obase + ch0 + 4) = make_float4(a4, a5, a6, a7);
    }
  }
}

extern "C" void kernel_launch(void* const* d_in, const int* in_sizes, int n_in,
                              void* d_out, int out_size, void* d_ws, size_t ws_size,
                              hipStream_t stream) {
  const float* x  = (const float*)d_in[0];   // (T,B,C)
  const float* Wl = (const float*)d_in[1];   // (H*K, C)
  const float* bl = (const float*)d_in[2];   // (H*K,)
  const float* cb = (const float*)d_in[3];   // (C,)
  float* out = (float*)d_out;                // (T,B,C)

  const bool prepped = ws_size >= 262144;    // 224KB frag-W, padded

  if (prepped) {
    uint16_t* wf = (uint16_t*)d_ws;
    prep_wfrag_kernel<<<(32 * 7 * 64) / 256, 256, 0, stream>>>(Wl, wf);
    fused_dynconv_kernel<true><<<TB / 16, 512, 0, stream>>>(x, Wl, wf, bl, cb, out);
  } else {
    fused_dynconv_kernel<false><<<TB / 16, 512, 0, stream>>>(x, Wl, nullptr, bl, cb, out);
  }
}

// Round 8
// 29.667 us; speedup vs baseline: 1.1209x; 1.0184x over previous
//
#include <hip/hip_runtime.h>
#include <stdint.h>

// Problem constants (from reference):
#define T_DIM 1024
#define B_DIM 8
#define C_DIM 1024
#define H_DIM 16
#define K_SZ  7
#define P_PAD 3
#define O_DIM (H_DIM * K_SZ)   // 112
#define TB    (T_DIM * B_DIM)  // 8192 rows

typedef __attribute__((ext_vector_type(8))) short bf16x8;  // 4 VGPRs, 8 bf16
typedef __attribute__((ext_vector_type(4))) float f32x4;
typedef __attribute__((ext_vector_type(4))) uint32_t u32x4;

union FragU { uint32_t u[4]; bf16x8 v; };

// RNE fp32->bf16 pack of two floats into one dword (lo=a, hi=b)
__device__ inline uint32_t pk_bf16(float a, float b) {
  uint32_t ua = __float_as_uint(a), ub = __float_as_uint(b);
  ua += 0x7FFFu + ((ua >> 16) & 1u);
  ub += 0x7FFFu + ((ub >> 16) & 1u);
  return (ua >> 16) | (ub & 0xFFFF0000u);
}

__device__ inline bf16x8 load_bf16x8_cvt(const float* __restrict__ p) {
  float4 lo = *reinterpret_cast<const float4*>(p);
  float4 hi = *reinterpret_cast<const float4*>(p + 4);
  FragU f;
  f.u[0] = pk_bf16(lo.x, lo.y);
  f.u[1] = pk_bf16(lo.z, lo.w);
  f.u[2] = pk_bf16(hi.x, hi.y);
  f.u[3] = pk_bf16(hi.z, hi.w);
  return f.v;
}

// Raw barrier: orders LDS producer->consumer across waves WITHOUT draining
// vmcnt (prefetch loads / conv stores stay in flight across phases).
__device__ inline void bar_lds() {
  __builtin_amdgcn_sched_barrier(0);
  asm volatile("s_waitcnt lgkmcnt(0)" ::: "memory");
  __builtin_amdgcn_s_barrier();
  __builtin_amdgcn_sched_barrier(0);
}

// Kernel 0: build fragment-native bf16 W.
// Wf[((ks*7)+nf)*64 + lane] (16B) = W[nf*16+(lane&15)][ks*32+(lane>>4)*8 .. +7]
__global__ __launch_bounds__(256) void prep_wfrag_kernel(
    const float* __restrict__ Wl, uint16_t* __restrict__ Wf) {
  const int t  = blockIdx.x * 256 + threadIdx.x;  // 0..14335
  const int f  = t >> 6;
  const int l  = t & 63;
  const int ks = f / 7;
  const int nf = f - ks * 7;
  const int row = nf * 16 + (l & 15);
  const int kb  = ks * 32 + (l >> 4) * 8;
  bf16x8 v = load_bf16x8_cvt(Wl + (size_t)row * C_DIM + kb);
  *reinterpret_cast<bf16x8*>(Wf + (size_t)t * 8) = v;   // coalesced 16B/lane
}

// Persistent pipelined fused kernel. 256 blocks x 1024 threads (16 waves/CU).
// Block owns 32 t-rows (two 16-row windows W0,W1) for one b, staged as bf16
// in a 32-slot LDS ring (slot = g&31, XOR-swizzle keyed on g&7).
//   prologue: stage rows t0-3..t0+18 (22)      [exposed]
//   issue prefetch rows t0+19..t0+34 -> regs   [HBM hides under W0 phases]
//   mfma W0 -> part; softmax -> wsm; conv W0 (stores)
//   write prefetch -> ring (slots reused only after conv W0)
//   mfma W1; softmax; conv W1
template <bool PREPPED>
__global__ __launch_bounds__(1024, 4) void fused_pipe_kernel(
    const float* __restrict__ x, const float* __restrict__ Wl,
    const uint16_t* __restrict__ Wf, const float* __restrict__ bl,
    const float* __restrict__ cb, float* __restrict__ out) {
  __shared__ char  ring[32 * 2048];     // 64KB: 32 bf16 rows, swizzled
  __shared__ float part[2][16][116];    // 14.5KB: per-K-half logits
  __shared__ float wsm[16][17][8];      // 8.7KB: softmax weights

  const int tid  = threadIdx.x;
  const int wv   = tid >> 6;            // 0..15
  const int lane = tid & 63;
  const int l15  = lane & 15;
  const int oct  = lane >> 4;

  // XCD swizzle: xcd owns 4 contiguous 32-row window-pairs for every b.
  const int bid = blockIdx.x;           // 0..255
  const int xcd = bid & 7;
  const int r8  = bid >> 3;             // 0..31
  const int b   = r8 >> 2;              // 0..7
  const int t0  = (xcd * 4 + (r8 & 3)) * 32;

  auto stage_write = [&](int task, int gbase) {
    const int q   = task >> 7;
    const int c16 = task & 127;
    const int g   = min(max(gbase + q, 0), T_DIM - 1);
    const float* __restrict__ src =
        x + ((size_t)(g * B_DIM + b)) * C_DIM + c16 * 8;
    float4 v0 = *reinterpret_cast<const float4*>(src);
    float4 v1 = *reinterpret_cast<const float4*>(src + 4);
    FragU f;
    f.u[0] = pk_bf16(v0.x, v0.y);
    f.u[1] = pk_bf16(v0.z, v0.w);
    f.u[2] = pk_bf16(v1.x, v1.y);
    f.u[3] = pk_bf16(v1.z, v1.w);
    const int dst = (g & 31) * 2048 + ((c16 * 16) ^ ((g & 7) << 4));
    *reinterpret_cast<bf16x8*>(ring + dst) = f.v;
  };

  auto mfma_phase = [&](int wbase) {
    if (wv < 14) {
      const int kh = (wv >= 7) ? 1 : 0;
      const int nf = wv - kh * 7;
      f32x4 acc = (f32x4)(0.f);
      const int ag   = wbase + l15;
      const char* ab = ring + (ag & 31) * 2048;
      const int axor = (ag & 7) << 4;
#pragma unroll
      for (int s = 0; s < 16; ++s) {
        const int ksg = kh * 16 + s;
        bf16x8 a = *reinterpret_cast<const bf16x8*>(
            ab + ((ksg * 64 + oct * 16) ^ axor));
        bf16x8 bf;
        if (PREPPED)
          bf = *reinterpret_cast<const bf16x8*>(
              Wf + ((size_t)((ksg * 7 + nf) * 64) + lane) * 8);
        else
          bf = load_bf16x8_cvt(Wl + (size_t)(nf * 16 + l15) * C_DIM + ksg * 32 + oct * 8);
        acc = __builtin_amdgcn_mfma_f32_16x16x32_bf16(a, bf, acc, 0, 0, 0);
      }
      // D layout: col = lane&15 (W row), row = (lane>>4)*4 + reg (x row)
#pragma unroll
      for (int rr = 0; rr < 4; ++rr)
        part[kh][oct * 4 + rr][nf * 16 + l15] = acc[rr];
    }
  };

  auto softmax_phase = [&]() {
    if (tid < 256) {
      const int row = tid >> 4;
      const int h   = tid & 15;
      float lg[7];
      float m = -1e30f;
#pragma unroll
      for (int j = 0; j < 7; ++j) {
        const int c = h * 7 + j;
        float s_ = part[0][row][c] + part[1][row][c] + bl[c];
        lg[j] = s_;
        m = fmaxf(m, s_);
      }
      float s = 0.f;
#pragma unroll
      for (int j = 0; j < 7; ++j) { lg[j] = __expf(lg[j] - m); s += lg[j]; }
      const float inv = 1.0f / s;
#pragma unroll
      for (int j = 0; j < 7; ++j) wsm[row][h][j] = lg[j] * inv;
    }
  };

  auto conv_phase = [&](int wbase) {
    const int row  = wv;               // one wave per output row
    const int gout = wbase + row;
    float okf[7];
    int slotb[7], sxor[7];
#pragma unroll
    for (int j = 0; j < 7; ++j) {
      const int tp = gout + j - P_PAD;
      okf[j] = (tp >= 0 && tp < T_DIM) ? 1.f : 0.f;
      const int g = min(max(tp, 0), T_DIM - 1);
      slotb[j] = (g & 31) * 2048;
      sxor[j]  = (g & 7) << 4;
    }
    float* __restrict__ obase = out + ((size_t)(gout * B_DIM + b)) * C_DIM;
#pragma unroll
    for (int ii = 0; ii < 2; ++ii) {
      const int ch0  = ii * 512 + lane * 8;
      const int head = ch0 >> 6;
      float4 w0 = *reinterpret_cast<const float4*>(&wsm[row][head][0]);
      float4 w1 = *reinterpret_cast<const float4*>(&wsm[row][head][4]);
      const float wj[7] = {w0.x, w0.y, w0.z, w0.w, w1.x, w1.y, w1.z};
      float4 c0 = *reinterpret_cast<const float4*>(cb + ch0);
      float4 c1 = *reinterpret_cast<const float4*>(cb + ch0 + 4);
      float a0 = c0.x, a1 = c0.y, a2 = c0.z, a3 = c0.w;
      float a4 = c1.x, a5 = c1.y, a6 = c1.z, a7 = c1.w;
#pragma unroll
      for (int j = 0; j < 7; ++j) {
        const float w = wj[j] * okf[j];
        const u32x4 d = *reinterpret_cast<const u32x4*>(
            ring + slotb[j] + ((ch0 * 2) ^ sxor[j]));
        a0 += w * __uint_as_float(d.x << 16);
        a1 += w * __uint_as_float(d.x & 0xffff0000u);
        a2 += w * __uint_as_float(d.y << 16);
        a3 += w * __uint_as_float(d.y & 0xffff0000u);
        a4 += w * __uint_as_float(d.z << 16);
        a5 += w * __uint_as_float(d.z & 0xffff0000u);
        a6 += w * __uint_as_float(d.w << 16);
        a7 += w * __uint_as_float(d.w & 0xffff0000u);
      }
      *reinterpret_cast<float4*>(obase + ch0)     = make_float4(a0, a1, a2, a3);
      *reinterpret_cast<float4*>(obase + ch0 + 4) = make_float4(a4, a5, a6, a7);
    }
  };

  // ---- prologue: stage rows t0-3 .. t0+18 (22 rows) ----
#pragma unroll
  for (int it = 0; it < 3; ++it) {
    const int task = tid + it * 1024;
    if (task < 22 * 128) stage_write(task, t0 - 3);
  }
  bar_lds();

  // ---- issue prefetch: rows t0+19 .. t0+34 (16 rows) into registers ----
  float4 pf0, pf1, pf2, pf3;
  {
    const int q0 = tid >> 7, c0_ = tid & 127;
    const int g0 = min(t0 + 19 + q0, T_DIM - 1);
    const float* __restrict__ s0 =
        x + ((size_t)(g0 * B_DIM + b)) * C_DIM + c0_ * 8;
    pf0 = *reinterpret_cast<const float4*>(s0);
    pf1 = *reinterpret_cast<const float4*>(s0 + 4);
    const int t2 = tid + 1024;
    const int q1 = t2 >> 7, c1_ = t2 & 127;
    const int g1 = min(t0 + 19 + q1, T_DIM - 1);
    const float* __restrict__ s1 =
        x + ((size_t)(g1 * B_DIM + b)) * C_DIM + c1_ * 8;
    pf2 = *reinterpret_cast<const float4*>(s1);
    pf3 = *reinterpret_cast<const float4*>(s1 + 4);
  }

  // ---- window 0 ----
  mfma_phase(t0);
  bar_lds();
  softmax_phase();
  bar_lds();
  conv_phase(t0);
  bar_lds();   // all conv-W0 tap reads retired before ring slots are reused

  // ---- write prefetch into ring (slots (t0+19..34)&31: dead after conv W0) ----
  {
    const int q0 = tid >> 7, c0_ = tid & 127;
    const int g0 = min(t0 + 19 + q0, T_DIM - 1);
    FragU f;
    f.u[0] = pk_bf16(pf0.x, pf0.y);
    f.u[1] = pk_bf16(pf0.z, pf0.w);
    f.u[2] = pk_bf16(pf1.x, pf1.y);
    f.u[3] = pk_bf16(pf1.z, pf1.w);
    *reinterpret_cast<bf16x8*>(
        ring + (g0 & 31) * 2048 + ((c0_ * 16) ^ ((g0 & 7) << 4))) = f.v;
    const int t2 = tid + 1024;
    const int q1 = t2 >> 7, c1_ = t2 & 127;
    const int g1 = min(t0 + 19 + q1, T_DIM - 1);
    FragU f2;
    f2.u[0] = pk_bf16(pf2.x, pf2.y);
    f2.u[1] = pk_bf16(pf2.z, pf2.w);
    f2.u[2] = pk_bf16(pf3.x, pf3.y);
    f2.u[3] = pk_bf16(pf3.z, pf3.w);
    *reinterpret_cast<bf16x8*>(
        ring + (g1 & 31) * 2048 + ((c1_ * 16) ^ ((g1 & 7) << 4))) = f2.v;
  }
  bar_lds();

  // ---- window 1 ----
  mfma_phase(t0 + 16);
  bar_lds();
  softmax_phase();
  bar_lds();
  conv_phase(t0 + 16);
}

extern "C" void kernel_launch(void* const* d_in, const int* in_sizes, int n_in,
                              void* d_out, int out_size, void* d_ws, size_t ws_size,
                              hipStream_t stream) {
  const float* x  = (const float*)d_in[0];   // (T,B,C)
  const float* Wl = (const float*)d_in[1];   // (H*K, C)
  const float* bl = (const float*)d_in[2];   // (H*K,)
  const float* cb = (const float*)d_in[3];   // (C,)
  float* out = (float*)d_out;                // (T,B,C)

  const bool prepped = ws_size >= 262144;    // 224KB frag-W, padded

  if (prepped) {
    uint16_t* wf = (uint16_t*)d_ws;
    prep_wfrag_kernel<<<(32 * 7 * 64) / 256, 256, 0, stream>>>(Wl, wf);
    fused_pipe_kernel<true><<<256, 1024, 0, stream>>>(x, Wl, wf, bl, cb, out);
  } else {
    fused_pipe_kernel<false><<<256, 1024, 0, stream>>>(x, Wl, nullptr, bl, cb, out);
  }
}